// Round 1
// 214.511 us; speedup vs baseline: 1.0683x; 1.0683x over previous
//
#include <hip/hip_runtime.h>

typedef __bf16 bf16x8 __attribute__((ext_vector_type(8)));
typedef __bf16 bf16x4 __attribute__((ext_vector_type(4)));
typedef __bf16 bf16x2 __attribute__((ext_vector_type(2)));
typedef float  floatx4 __attribute__((ext_vector_type(4)));
typedef unsigned int uint32;
typedef uint32 uintx4 __attribute__((ext_vector_type(4)));

#define MFMA16(a,b,c) __builtin_amdgcn_mfma_f32_16x16x32_bf16(a,b,c,0,0,0)

constexpr int DIM  = 512;
constexpr int SEQ  = 4096;
constexpr int HD   = 64;
// 0.125 (HEAD_DIM^-0.5) * log2(e), folded into Q so softmax uses exp2 directly
constexpr float QSCALE = 0.1803368801111244f;

static __device__ inline __bf16 f2bf(float f) {
    unsigned int u = __builtin_bit_cast(unsigned int, f);
    u += 0x7fffu + ((u >> 16) & 1u);
    return __builtin_bit_cast(__bf16, (unsigned short)(u >> 16));
}
#if __has_builtin(__builtin_amdgcn_cvt_pk_bf16_f32)
static __device__ inline bf16x2 pk2(float a, float b) {
    return __builtin_amdgcn_cvt_pk_bf16_f32(a, b);
}
#else
static __device__ inline bf16x2 pk2(float a, float b) {
    bf16x2 r; r[0] = f2bf(a); r[1] = f2bf(b); return r;
}
#endif
#if __has_builtin(__builtin_amdgcn_exp2f)
#define EXP2(x) __builtin_amdgcn_exp2f(x)
#else
#define EXP2(x) exp2f(x)
#endif
static __device__ inline bf16x8 cvt8(floatx4 lo, floatx4 hi) {
    uintx4 w;
    w[0] = __builtin_bit_cast(uint32, pk2(lo[0], lo[1]));
    w[1] = __builtin_bit_cast(uint32, pk2(lo[2], lo[3]));
    w[2] = __builtin_bit_cast(uint32, pk2(hi[0], hi[1]));
    w[3] = __builtin_bit_cast(uint32, pk2(hi[2], hi[3]));
    return __builtin_bit_cast(bf16x8, w);
}

// async global->LDS, 16B per lane; LDS dest = wave-uniform base + lane*16B
static __device__ inline void gload16(const __bf16* g, __bf16* l) {
#if __has_builtin(__builtin_amdgcn_global_load_lds)
    __builtin_amdgcn_global_load_lds(
        (const __attribute__((address_space(1))) unsigned int*)g,
        (__attribute__((address_space(3))) unsigned int*)l, 16, 0, 0);
#else
    *(bf16x8*)(l + (threadIdx.x & 63)*8) = *(const bf16x8*)g;
#endif
}

// Blocked fragment layout for Q and K (A/B-operand ready, b128 loads):
//   blk[bh][s>>4][d>>5][lane][8], lane = ((d>>3)&3)*16 + (s&15), slot = d&7
// V blocked under key-permutation pi(q,j)=16*(j>=4)+4q+(j&3):
//   Vblk[bh][s>>5][d>>4][lane][8], lane = ((s>>2)&3)*16 + (d&15),
//   slot j = (s&3) + ((s>>4)&1)*4.

// ---------------------------------------------------------------------------
// Stage 1: qkv = x @ w_qkv^T + b_qkv.  R8: double-buffered LDS (1 barrier per
// k-iter instead of 2) + register prefetch of the next fp32 panel issued at
// iter top, so global latency hides under ds_read+MFMA of the current panel.
// ---------------------------------------------------------------------------
__global__ __launch_bounds__(256)
void gemm_qkv(const float* __restrict__ X, const float* __restrict__ W,
              const float* __restrict__ bias,
              __bf16* __restrict__ Qb, __bf16* __restrict__ Kb, __bf16* __restrict__ Vb)
{
    __shared__ __bf16 As[2][128*32];
    __shared__ __bf16 Bs[2][128*32];
    const int tid  = threadIdx.x;
    const int lane = tid & 63;
    const int wave = tid >> 6;
    const int quad = lane >> 4;
    const int l16  = lane & 15;
    const int waveM = wave >> 1, waveN = wave & 1;
    const int mBase = blockIdx.x * 128;
    const int nBase = blockIdx.y * 128;
    const int which = nBase >> 9;          // 0=q 1=k 2=v (uniform per block)

    floatx4 zero = {0.f, 0.f, 0.f, 0.f};
    floatx4 acc[4][4];
    for (int i = 0; i < 4; i++)
        for (int j = 0; j < 4; j++) acc[i][j] = zero;

    const int srow = tid >> 2;        // 0..63
    const int scol = (tid & 3) * 8;   // 0,8,16,24

    const float* xp0 = X + (size_t)(mBase + srow)      * DIM + scol;
    const float* xp1 = X + (size_t)(mBase + 64 + srow) * DIM + scol;
    const float* wp0 = W + (size_t)(nBase + srow)      * DIM + scol;
    const float* wp1 = W + (size_t)(nBase + 64 + srow) * DIM + scol;

    floatx4 r[8];
    auto LOAD = [&](int k0) {
        r[0] = *(const floatx4*)(xp0 + k0); r[1] = *(const floatx4*)(xp0 + k0 + 4);
        r[2] = *(const floatx4*)(xp1 + k0); r[3] = *(const floatx4*)(xp1 + k0 + 4);
        r[4] = *(const floatx4*)(wp0 + k0); r[5] = *(const floatx4*)(wp0 + k0 + 4);
        r[6] = *(const floatx4*)(wp1 + k0); r[7] = *(const floatx4*)(wp1 + k0 + 4);
    };
    auto STORE = [&](int b) {
        *(bf16x8*)&As[b][srow*32 + scol]      = cvt8(r[0], r[1]);
        *(bf16x8*)&As[b][(64+srow)*32 + scol] = cvt8(r[2], r[3]);
        *(bf16x8*)&Bs[b][srow*32 + scol]      = cvt8(r[4], r[5]);
        *(bf16x8*)&Bs[b][(64+srow)*32 + scol] = cvt8(r[6], r[7]);
    };

    LOAD(0);
    STORE(0);
    __syncthreads();

    for (int it = 0; it < 16; ++it) {
        const int cur = it & 1;
        if (it < 15) LOAD((it + 1) * 32);   // prefetch next panel (hidden latency)

        bf16x8 af[4], bfr[4];
        for (int mi = 0; mi < 4; mi++)
            af[mi]  = *(const bf16x8*)&As[cur][(waveM*64 + mi*16 + l16)*32 + quad*8];
        for (int ni = 0; ni < 4; ni++)
            bfr[ni] = *(const bf16x8*)&Bs[cur][(waveN*64 + ni*16 + l16)*32 + quad*8];
        if (which == 2) {
            for (int mi = 0; mi < 4; mi++)
                for (int ni = 0; ni < 4; ni++)
                    acc[mi][ni] = MFMA16(af[mi], bfr[ni], acc[mi][ni]);
        } else {
            // transposed: rows = W-rows (d), cols = X-rows (s)
            for (int mi = 0; mi < 4; mi++)
                for (int ni = 0; ni < 4; ni++)
                    acc[mi][ni] = MFMA16(bfr[ni], af[mi], acc[mi][ni]);
        }
        if (it < 15) STORE(cur ^ 1);        // writes go to the other buffer
        __syncthreads();                    // one barrier per iter
    }

    if (which == 2) {
        // V epilogue (normal orientation): rows = s, cols = n/d
        for (int ni = 0; ni < 4; ni++) {
            const int n = nBase + waveN*64 + ni*16 + l16;
            const float bv = bias[n];
            const int h = (n >> 6) & 7;
            const int d = n & 63;
            for (int mi = 0; mi < 4; mi++) {
                const int m0 = mBase + waveM*64 + mi*16 + quad*4;
                const int b  = m0 >> 12;
                const int s0 = m0 & 4095;
                const int bh = (b << 3) | h;
                bf16x4 v;
                for (int rr = 0; rr < 4; rr++) v[rr] = f2bf(acc[mi][ni][rr] + bv);
                size_t off = (((((size_t)bh*128 + (s0 >> 5))*4 + (d >> 4))*64)
                              + ((s0 >> 2) & 3)*16 + (d & 15))*8 + ((s0 >> 4) & 1)*4;
                *(bf16x4*)&Vb[off] = v;
            }
        }
    } else {
        // Q/K epilogue (transposed): rows = d (quad*4+r), cols = s (l16)
        __bf16* dst = (which == 0) ? Qb : Kb;
        for (int ni = 0; ni < 4; ni++) {
            const int n0 = nBase + waveN*64 + ni*16 + quad*4;
            const floatx4 b4 = *(const floatx4*)&bias[n0];
            const int dfull = n0 & 511;           // 0..511 within q or k section
            const int h  = dfull >> 6;
            const int d0 = dfull & 63;            // 4-aligned
            const int lgrp = ((d0 >> 3) & 3)*16 + l16;
            const int half = d0 >> 5;
            const int slot = d0 & 7;              // 0 or 4
            for (int mi = 0; mi < 4; mi++) {
                const int m = mBase + waveM*64 + mi*16 + l16;
                const int b = m >> 12, s = m & 4095;
                const int bh = (b << 3) | h;
                bf16x4 v;
                for (int rr = 0; rr < 4; rr++) {
                    float val = acc[mi][ni][rr] + b4[rr];
                    if (which == 0) val *= QSCALE;
                    v[rr] = f2bf(val);
                }
                size_t off = ((((size_t)bh*256 + (s >> 4))*2 + half)*64 + lgrp)*8 + slot;
                *(bf16x4*)&dst[off] = v;
            }
        }
    }
}

// ---------------------------------------------------------------------------
// Stage 2: flash attention.  R8: chunk-ahead K/V register double-buffer
// (2x-unrolled, static reg sets) hides the per-chunk global-load latency that
// the counters showed as ~40% idle; s_setprio(1) around MFMA clusters (T5,
// attn-regime +4-7%); launch_bounds(256,2) so the prefetch regs don't spill
// and the 4-blocks/CU grid runs as clean 2+2 rounds.
// ---------------------------------------------------------------------------
__global__ __launch_bounds__(256, 2)
void attn_kernel(const __bf16* __restrict__ Qb, const __bf16* __restrict__ Kb,
                 const __bf16* __restrict__ Vb, __bf16* __restrict__ Ao)
{
    __shared__ __bf16 Ob[3][64*68];   // bf16 partial O^T, stride 68
    __shared__ float  Lb[4][64];
    const int tid  = threadIdx.x;
    const int lane = tid & 63;
    const int wave = tid >> 6;
    const int quad = lane >> 4;
    const int l16  = lane & 15;
    const int bh    = blockIdx.x;         // 0..15
    const int qBase = blockIdx.y * 64;

    const __bf16* qg = Qb + (size_t)bh*256*2*512;
    const __bf16* kg = Kb + (size_t)bh*256*2*512;
    const __bf16* vg = Vb + (size_t)bh*128*4*512;

    bf16x8 qf[4][2];
    for (int t = 0; t < 4; t++)
        for (int hb = 0; hb < 2; hb++)
            qf[t][hb] = *(const bf16x8*)(qg
                + ((size_t)((qBase >> 4) + t)*2 + hb)*512 + lane*8);

    floatx4 zero = {0.f, 0.f, 0.f, 0.f};
    floatx4 oacc[4][4];   // [t][od]: O^T tile, row d=od*16+quad*4+r, col q=t*16+l16
    for (int t = 0; t < 4; t++)
        for (int od = 0; od < 4; od++) oacc[t][od] = zero;
    floatx4 Lt[4];        // ones-MFMA: every row of Lt[t] = L[q=t*16+l16]
    for (int t = 0; t < 4; t++) Lt[t] = zero;

    bf16x8 ones;
    for (int j = 0; j < 8; j++) ones[j] = f2bf(1.0f);

    const int kvBase = wave * 32;     // chunk index base (each chunk = 32 keys)

    auto LOADKV = [&](int cc, bf16x8 (&kb)[4], bf16x8 (&vb)[4]) {
        const __bf16* kp = kg + (size_t)(kvBase + cc)*2048 + lane*8;
        const __bf16* vp = vg + (size_t)(kvBase + cc)*2048 + lane*8;
        kb[0] = *(const bf16x8*)(kp);
        kb[1] = *(const bf16x8*)(kp + 512);
        kb[2] = *(const bf16x8*)(kp + 1024);
        kb[3] = *(const bf16x8*)(kp + 1536);
        vb[0] = *(const bf16x8*)(vp);
        vb[1] = *(const bf16x8*)(vp + 512);
        vb[2] = *(const bf16x8*)(vp + 1024);
        vb[3] = *(const bf16x8*)(vp + 1536);
    };
    auto COMPUTE = [&](bf16x8 (&kb)[4], bf16x8 (&vb)[4]) {
        for (int t = 0; t < 4; t++) {
            floatx4 z0 = zero, z1 = zero;
            __builtin_amdgcn_s_setprio(1);
            z0 = MFMA16(kb[0], qf[t][0], z0);
            z0 = MFMA16(kb[1], qf[t][1], z0);
            z1 = MFMA16(kb[2], qf[t][0], z1);
            z1 = MFMA16(kb[3], qf[t][1], z1);
            __builtin_amdgcn_s_setprio(0);
            float e0[4], e1[4];
            for (int rr = 0; rr < 4; rr++) { e0[rr] = EXP2(z0[rr]); e1[rr] = EXP2(z1[rr]); }
            uintx4 w;
            w[0] = __builtin_bit_cast(uint32, pk2(e0[0], e0[1]));
            w[1] = __builtin_bit_cast(uint32, pk2(e0[2], e0[3]));
            w[2] = __builtin_bit_cast(uint32, pk2(e1[0], e1[1]));
            w[3] = __builtin_bit_cast(uint32, pk2(e1[2], e1[3]));
            bf16x8 pb = __builtin_bit_cast(bf16x8, w);
            __builtin_amdgcn_s_setprio(1);
            Lt[t] = MFMA16(ones, pb, Lt[t]);
            oacc[t][0] = MFMA16(vb[0], pb, oacc[t][0]);
            oacc[t][1] = MFMA16(vb[1], pb, oacc[t][1]);
            oacc[t][2] = MFMA16(vb[2], pb, oacc[t][2]);
            oacc[t][3] = MFMA16(vb[3], pb, oacc[t][3]);
            __builtin_amdgcn_s_setprio(0);
        }
    };

    // software pipeline: two static K/V register sets, one chunk ahead
    bf16x8 ka[4], va[4], kb2[4], vb2[4];
    LOADKV(0, ka, va);
    for (int c = 0; c < 32; c += 2) {
        LOADKV(c + 1, kb2, vb2);
        COMPUTE(ka, va);
        if (c + 2 < 32) LOADKV(c + 2, ka, va);
        COMPUTE(kb2, vb2);
    }

    // L[q] is replicated across rows of Lt[t]; publish per-wave partials
    if (lane < 16)
        for (int t = 0; t < 4; t++) Lb[wave][t*16 + lane] = Lt[t][0];
    __syncthreads();
    float inv[4];
    for (int t = 0; t < 4; t++) {
        const int q = t*16 + l16;
        inv[t] = 1.0f / (Lb[0][q] + Lb[1][q] + Lb[2][q] + Lb[3][q]);
    }
    if (wave != 0) {
        for (int t = 0; t < 4; t++)
            for (int od = 0; od < 4; od++) {
                bf16x4 v;
                for (int rr = 0; rr < 4; rr++) v[rr] = f2bf(oacc[t][od][rr] * inv[t]);
                *(bf16x4*)&Ob[wave-1][(t*16 + l16)*68 + od*16 + quad*4] = v;
            }
    }
    __syncthreads();
    if (wave == 0) {
        const int b = bh >> 3, h = bh & 7;
        for (int t = 0; t < 4; t++) {
            const int s = qBase + t*16 + l16;
            for (int od = 0; od < 4; od++) {
                bf16x4 o0 = *(const bf16x4*)&Ob[0][(t*16 + l16)*68 + od*16 + quad*4];
                bf16x4 o1 = *(const bf16x4*)&Ob[1][(t*16 + l16)*68 + od*16 + quad*4];
                bf16x4 o2 = *(const bf16x4*)&Ob[2][(t*16 + l16)*68 + od*16 + quad*4];
                bf16x4 v;
                for (int rr = 0; rr < 4; rr++) {
                    float o = oacc[t][od][rr] * inv[t] +
                              (float)o0[rr] + (float)o1[rr] + (float)o2[rr];
                    v[rr] = f2bf(o);
                }
                *(bf16x4*)&Ao[((size_t)(b*SEQ + s))*DIM + h*HD + od*16 + quad*4] = v;
            }
        }
    }
}

// ---------------------------------------------------------------------------
// Stage 3: out = attn_out @ w_proj^T + b_proj.  R8: 64x64 tiles -> grid
// (128,8) = 1024 blocks (was 256 = 1 block/CU, fully latency-exposed),
// double-buffered LDS, A staged via global_load_lds into the next buffer,
// W reg-prefetched + inline cvt.  One barrier per k-iter.
// ---------------------------------------------------------------------------
__global__ __launch_bounds__(256)
void gemm_proj(const __bf16* __restrict__ A, const float* __restrict__ W,
               const float* __restrict__ bias, float* __restrict__ Out)
{
    __shared__ __bf16 As[2][64*32];
    __shared__ __bf16 Bs[2][64*32];
    const int tid  = threadIdx.x;
    const int lane = tid & 63;
    const int wave = tid >> 6;
    const int quad = lane >> 4;
    const int l16  = lane & 15;
    const int waveM = wave >> 1, waveN = wave & 1;
    const int mBase = blockIdx.x * 64;
    const int nBase = blockIdx.y * 64;

    floatx4 zero = {0.f, 0.f, 0.f, 0.f};
    floatx4 acc[2][2];
    for (int i = 0; i < 2; i++)
        for (int j = 0; j < 2; j++) acc[i][j] = zero;

    const int srow = tid >> 2;          // 0..63
    const int scol = (tid & 3) * 8;     // 0,8,16,24

    // A: 64 rows x 32 cols bf16 per iter = 4KB = 16B/lane, wave w stages rows
    // [w*16, w*16+16): LDS linear offset = lane*8 elems from wave base.
    const __bf16* gA = A + (size_t)(mBase + wave*16 + (lane >> 2))*DIM + (lane & 3)*8;
    const float*  gW = W + (size_t)(nBase + srow)*DIM + scol;

    floatx4 rw0, rw1;
    gload16(gA, &As[0][wave*512]);
    rw0 = *(const floatx4*)(gW);
    rw1 = *(const floatx4*)(gW + 4);
    *(bf16x8*)&Bs[0][srow*32 + scol] = cvt8(rw0, rw1);
    __syncthreads();

    for (int it = 0; it < 16; ++it) {
        const int cur = it & 1;
        if (it < 15) {
            gload16(gA + (it + 1)*32, &As[cur ^ 1][wave*512]);
            rw0 = *(const floatx4*)(gW + (it + 1)*32);
            rw1 = *(const floatx4*)(gW + (it + 1)*32 + 4);
        }
        bf16x8 af[2], bfr[2];
        for (int mi = 0; mi < 2; mi++)
            af[mi]  = *(const bf16x8*)&As[cur][(waveM*32 + mi*16 + l16)*32 + quad*8];
        for (int ni = 0; ni < 2; ni++)
            bfr[ni] = *(const bf16x8*)&Bs[cur][(waveN*32 + ni*16 + l16)*32 + quad*8];
        for (int mi = 0; mi < 2; mi++)
            for (int ni = 0; ni < 2; ni++)
                acc[mi][ni] = MFMA16(af[mi], bfr[ni], acc[mi][ni]);
        if (it < 15)
            *(bf16x8*)&Bs[cur ^ 1][srow*32 + scol] = cvt8(rw0, rw1);
        __syncthreads();   // drains gload_lds (vmcnt) and ds_writes
    }

    for (int ni = 0; ni < 2; ni++) {
        const int n = nBase + waveN*32 + ni*16 + l16;
        const float bv = bias[n];
        for (int mi = 0; mi < 2; mi++) {
            const int m0 = mBase + waveM*32 + mi*16 + quad*4;
            for (int rr = 0; rr < 4; rr++)
                Out[(size_t)(m0 + rr)*DIM + n] = acc[mi][ni][rr] + bv;
        }
    }
}

extern "C" void kernel_launch(void* const* d_in, const int* in_sizes, int n_in,
                              void* d_out, int out_size, void* d_ws, size_t ws_size,
                              hipStream_t stream) {
    const float* x      = (const float*)d_in[0];   // [2,4096,512] fp32
    const float* w_qkv  = (const float*)d_in[1];   // [1536,512] fp32
    const float* b_qkv  = (const float*)d_in[2];   // [1536] fp32
    const float* w_proj = (const float*)d_in[3];   // [512,512] fp32
    const float* b_proj = (const float*)d_in[4];   // [512] fp32
    float* out = (float*)d_out;                    // [2,4096,512] fp32

    __bf16* ws  = (__bf16*)d_ws;
    const size_t PLANE = (size_t)16 * SEQ * HD;    // 4 Mi elements = 8 MB
    __bf16* Qbk = ws;                 // Qblk [16][256][2][64][8] (pre-scaled)
    __bf16* Kbk = ws + PLANE;         // Kblk [16][256][2][64][8]
    __bf16* Vbk = ws + 2*PLANE;       // Vblk [16][128][4][64][8]
    __bf16* Aob = ws + 3*PLANE;       // [2,4096,512] attention output (bf16)

    gemm_qkv<<<dim3(64, 12), 256, 0, stream>>>(x, w_qkv, b_qkv, Qbk, Kbk, Vbk);
    attn_kernel<<<dim3(16, 64), 256, 0, stream>>>(Qbk, Kbk, Vbk, Aob);
    gemm_proj<<<dim3(128, 8), 256, 0, stream>>>(Aob, w_proj, b_proj, out);
}